// Round 11
// baseline (1087.978 us; speedup 1.0000x reference)
//
#include <hip/hip_runtime.h>
#include <stdint.h>

typedef unsigned short u16;
typedef unsigned int u32;

#define B_ 32
#define L_ 512
#define T_ 4096
#define E_ 256
#define F_ 256

// ---------------- fp32 duration predictor params ----------------
#define TW 16          // output positions per block (fp32 kernel)
#define NH (TW + 2)
#define NX (TW + 4)
#define RS 20

// ---------------- MFMA predictor params ----------------
#define MTW 62         // valid outputs per block
#define MROWS 64       // conv M rows per block (padded)
#define XROWS 66       // staged x rows (t0-2 .. t0+63)
#define XSTR 264       // u16 per LDS row (528 B) -> (nl+quad)%8 bank-group tiling
#define NBLK 67        // ceil(4096/62)
#define KW 768         // GEMM K (3*256)
#define WMAT (KW * F_) // 196608 elements per transposed weight matrix

typedef short bf16x8 __attribute__((ext_vector_type(8)));
typedef float f32x4 __attribute__((ext_vector_type(4)));
union Frag { uint4 u; bf16x8 b; };

__device__ __forceinline__ u16 f2b(float f) {
    union { u32 i; float f; } x; x.f = f;
    u32 r = x.i + 0x7FFFu + ((x.i >> 16) & 1u);
    return (u16)(r >> 16);
}

// packed f32x2 -> bf16x2 (RNE), 1 VALU op
__device__ __forceinline__ u32 cvt_pk(float lo, float hi) {
    u32 r;
    asm("v_cvt_pk_bf16_f32 %0, %1, %2" : "=v"(r) : "v"(lo), "v"(hi));
    return r;
}
__device__ __forceinline__ u16 f2b1(float f) {
    u32 r;
    asm("v_cvt_pk_bf16_f32 %0, %1, %2" : "=v"(r) : "v"(f), "v"(f));
    return (u16)r;
}

// ---------- weight prep: fp32 [kk][f] -> bf16 transposed [f][kk] ----------
// mats: 0=pitch.w1 1=pitch.w2 2=energy.w1 3=energy.w2
__global__ void prep_w_kernel(const float* __restrict__ W1all,
                              const float* __restrict__ W2all,
                              u16* __restrict__ dst) {
    const int g = blockIdx.x * 256 + threadIdx.x;      // 4*196608 total
    const int mat = g / WMAT, rem = g % WMAT;
    const int kk = rem >> 8, f = rem & 255;
    const float* src = ((mat & 1) ? W2all : W1all) + ((mat >> 1) + 1) * (3 * E_ * F_);
    dst[mat * WMAT + f * KW + kk] = f2b(src[kk * 256 + f]);
}

// ---------- cumsum of durations: csg[b][l] = sum_{j<=l} dur[b][j] ----------
__global__ __launch_bounds__(512) void cumsum_kernel(const int* __restrict__ dur,
                                                     int* __restrict__ csg) {
    __shared__ int cs[L_];
    const int b = blockIdx.x, tid = threadIdx.x;
    cs[tid] = dur[b * L_ + tid];
    __syncthreads();
    for (int off = 1; off < L_; off <<= 1) {
        int t = (tid >= off) ? cs[tid - off] : 0;
        __syncthreads();
        cs[tid] += t;
        __syncthreads();
    }
    csg[b * L_ + tid] = cs[tid];
}

// ---------- conv GEMM (R7 proven form: depth-1 B reg prefetch + setprio) ----------
// A-frag: lane(m=nl, k=quad*8+j); B-frag: lane(n=nl, k=quad*8+j); WT layout [n][kk]
__device__ __forceinline__ void conv_gemm(const u16* xs, const u16* __restrict__ WT,
                                          int col0, int nl, int quad, f32x4 acc[4][4]) {
#pragma unroll
    for (int mt = 0; mt < 4; ++mt)
#pragma unroll
        for (int nt = 0; nt < 4; ++nt) acc[mt][nt] = (f32x4){0.f, 0.f, 0.f, 0.f};
    const u16* wp0 = WT + (size_t)col0 * KW + quad * 8;
    Frag bq[4], bn[4];
#pragma unroll
    for (int nt = 0; nt < 4; ++nt) bq[nt].u = *(const uint4*)(wp0 + nt * (16 * KW));
    for (int s = 0; s < 24; ++s) {
        const int sp = (s + 1 < 24) ? s + 1 : 0;   // uniform clamp, in-bounds
#pragma unroll
        for (int nt = 0; nt < 4; ++nt)
            bn[nt].u = *(const uint4*)(wp0 + nt * (16 * KW) + sp * 32);
        const int kh = s >> 3, c0 = (s & 7) * 32;
        Frag a[4];
#pragma unroll
        for (int mt = 0; mt < 4; ++mt)
            a[mt].u = *(const uint4*)&xs[(16 * mt + nl + kh) * XSTR + c0 + quad * 8];
        __builtin_amdgcn_s_setprio(1);
#pragma unroll
        for (int mt = 0; mt < 4; ++mt)
#pragma unroll
            for (int nt = 0; nt < 4; ++nt)
                acc[mt][nt] = __builtin_amdgcn_mfma_f32_16x16x32_bf16(
                    a[mt].b, bq[nt].b, acc[mt][nt], 0, 0, 0);
        __builtin_amdgcn_s_setprio(0);
#pragma unroll
        for (int nt = 0; nt < 4; ++nt) bq[nt] = bn[nt];
    }
}

// ---------- combined pitch+energy MFMA predictor ----------
// grid = 2*B*NBLK. mat = 0: pitch, input x = LR(hidden).
//                  mat = 1: energy, input x2 = LR(hidden) + pemb[bucket(pt)];
//                           ALSO writes ve = (x + pemb) + eemb[bucket(et)] for its
//                           owned rows during staging (replaces ve_kernel).
// (256,3): cap unified regs at ~168 (arch ~104 + 64 AGPR) -> 3 waves/SIMD
// (was 116+64=180 -> 2). LDS 42.5KB x 3 blocks = 127.5 <= 160 KB.
__global__ __launch_bounds__(256, 3) void mfma_pe_kernel(
    const float* __restrict__ hidden, const int* __restrict__ csg,
    const float* __restrict__ pt, const float* __restrict__ pbins,
    const float* __restrict__ pemb,
    const float* __restrict__ et, const float* __restrict__ ebins,
    const float* __restrict__ eemb, float* __restrict__ ve,
    const u16* __restrict__ wt,
    const float* __restrict__ b1a, const float* __restrict__ s1a, const float* __restrict__ bb1a,
    const float* __restrict__ b2a, const float* __restrict__ s2a, const float* __restrict__ bb2a,
    const float* __restrict__ lwa, const float* __restrict__ lba,
    float* __restrict__ out_pitch, float* __restrict__ out_energy) {
    __shared__ u16 xs[XROWS * XSTR];          // 34.8 KB; x tile, then h1 tile
    __shared__ float2 red[MROWS][4];
    __shared__ float m_l[MROWS], inv_l[MROWS];
    __shared__ int cs_l[L_];
    __shared__ float bins_l[256];
    __shared__ float bins2_l[256];
    __shared__ int idx_l[XROWS];              // gather source row (-1 = zero)
    __shared__ int kb_l[XROWS];               // pemb bucket per row (mat=1)
    __shared__ int kb2_l[XROWS];              // eemb bucket per row (mat=1)

    const int tid = threadIdx.x;
    const int lane = tid & 63, w = tid >> 6;
    const int nl = lane & 15, quad = lane >> 4;
    const int mat = blockIdx.x / (B_ * NBLK);
    const int rem = blockIdx.x % (B_ * NBLK);
    const int b = rem / NBLK, blk = rem % NBLK;
    const int t0 = blk * MTW;
    const float* Xb = hidden + (size_t)b * (L_ * E_);

    const u16* WT1 = wt + (size_t)(2 * mat) * WMAT;
    const u16* WT2 = wt + (size_t)(2 * mat + 1) * WMAT;
    const float* B1 = b1a + (1 + mat) * F_;
    const float* S1 = s1a + (1 + mat) * F_;
    const float* Bb1 = bb1a + (1 + mat) * F_;
    const float* B2 = b2a + (1 + mat) * F_;
    const float* S2 = s2a + (1 + mat) * F_;
    const float* Bb2 = bb2a + (1 + mat) * F_;
    const float* LW = lwa + (1 + mat) * F_;
    const float lbv = lba[1 + mat];
    float* outp = mat ? out_energy : out_pitch;

    cs_l[tid] = csg[b * L_ + tid];
    cs_l[tid + 256] = csg[b * L_ + 256 + tid];
    if (mat) { bins_l[tid] = pbins[tid]; bins2_l[tid] = ebins[tid]; }
    __syncthreads();
    if (tid < XROWS) {
        const int tt = t0 - 2 + tid;
        int lo = 0, hi = L_;
        while (lo < hi) { int mid = (lo + hi) >> 1; if (cs_l[mid] <= tt) lo = mid + 1; else hi = mid; }
        const bool val = (tt >= 0) && (tt < T_) && (tt < cs_l[L_ - 1]);
        idx_l[tid] = val ? (lo < L_ - 1 ? lo : L_ - 1) : -1;
        int kb = 0, kb2 = 0;
        if (mat && tt >= 0 && tt < T_) {
            const float v = pt[b * T_ + tt];
            int lo2 = 0, hi2 = 256;
            while (lo2 < hi2) { int mid = (lo2 + hi2) >> 1; if (bins_l[mid] < v) lo2 = mid + 1; else hi2 = mid; }
            kb = lo2 > 255 ? 255 : lo2;
            const float v2 = et[b * T_ + tt];
            int lo3 = 0, hi3 = 256;
            while (lo3 < hi3) { int mid = (lo3 + hi3) >> 1; if (bins2_l[mid] < v2) lo3 = mid + 1; else hi3 = mid; }
            kb2 = lo3 > 255 ? 255 : lo3;
        }
        kb_l[tid] = kb;
        kb2_l[tid] = kb2;
    }
    __syncthreads();

    // ---- stage rows 0..65 (pos t0-2+i) as bf16; mat=1 also writes ve ----
    for (int it = 0; it < 17; ++it) {
        const int e = it * 256 + tid;                 // float4 units over 66*64
        if (e < XROWS * 64) {
            const int row = e >> 6, c4 = e & 63;
            const int tt = t0 - 2 + row;
            float4 v = make_float4(0.f, 0.f, 0.f, 0.f);
            const int id = idx_l[row];
            if (id >= 0) v = *(const float4*)(Xb + (size_t)id * E_ + c4 * 4);
            if (mat && tt >= 0 && tt < T_) {
                const float4 ev = *(const float4*)(pemb + (size_t)kb_l[row] * E_ + c4 * 4);
                v.x += ev.x; v.y += ev.y; v.z += ev.z; v.w += ev.w;
                if (row >= 2 && row < 64) {           // owned rows: disjoint across blocks
                    const float4 ee = *(const float4*)(eemb + (size_t)kb2_l[row] * E_ + c4 * 4);
                    float4 o = make_float4(v.x + ee.x, v.y + ee.y, v.z + ee.z, v.w + ee.w);
                    *(float4*)(ve + ((size_t)(b * T_ + tt)) * E_ + c4 * 4) = o;
                }
            }
            uint2 pk = make_uint2(cvt_pk(v.x, v.y), cvt_pk(v.z, v.w));
            *(uint2*)&xs[row * XSTR + c4 * 4] = pk;
        }
    }
    __syncthreads();

    const int col0 = w * 64 + nl;
    f32x4 acc[4][4];

    // ================= conv1 =================
    conv_gemm(xs, WT1, col0, nl, quad, acc);

    float pb[4], ps[4], pbb[4];
#pragma unroll
    for (int nt = 0; nt < 4; ++nt) {
        pb[nt] = B1[col0 + nt * 16]; ps[nt] = S1[col0 + nt * 16]; pbb[nt] = Bb1[col0 + nt * 16];
    }
#pragma unroll
    for (int mt = 0; mt < 4; ++mt)
#pragma unroll
        for (int nt = 0; nt < 4; ++nt)
#pragma unroll
            for (int r = 0; r < 4; ++r)
                acc[mt][nt][r] = fmaxf(acc[mt][nt][r] + pb[nt], 0.f);
    // LN1 stats
#pragma unroll
    for (int mt = 0; mt < 4; ++mt)
#pragma unroll
        for (int r = 0; r < 4; ++r) {
            float s = acc[mt][0][r] + acc[mt][1][r] + acc[mt][2][r] + acc[mt][3][r];
            float q = acc[mt][0][r] * acc[mt][0][r] + acc[mt][1][r] * acc[mt][1][r] +
                      acc[mt][2][r] * acc[mt][2][r] + acc[mt][3][r] * acc[mt][3][r];
#pragma unroll
            for (int off = 1; off < 16; off <<= 1) { s += __shfl_xor(s, off); q += __shfl_xor(q, off); }
            if (nl == 0) red[16 * mt + 4 * quad + r][w] = make_float2(s, q);
        }
    __syncthreads();
    if (tid < MROWS) {
        const float2 p0 = red[tid][0], p1 = red[tid][1], p2 = red[tid][2], p3 = red[tid][3];
        const float s = p0.x + p1.x + p2.x + p3.x, q = p0.y + p1.y + p2.y + p3.y;
        const float m = s * (1.f / 256.f);
        const float var = q * (1.f / 256.f) - m * m;
        m_l[tid] = m; inv_l[tid] = 1.f / sqrtf(var + 1e-5f);
    }
    __syncthreads();
    // normalize -> h1 tile (reuse xs), zero-pad h1 outside sequence
#pragma unroll
    for (int mt = 0; mt < 4; ++mt)
#pragma unroll
        for (int r = 0; r < 4; ++r) {
            const int row = 16 * mt + 4 * quad + r;
            const int th = t0 - 1 + row;
            const float mm = m_l[row], iv = inv_l[row];
#pragma unroll
            for (int nt = 0; nt < 4; ++nt) {
                float y = (acc[mt][nt][r] - mm) * iv * ps[nt] + pbb[nt];
                if (th < 0 || th >= T_) y = 0.f;
                xs[row * XSTR + col0 + nt * 16] = f2b1(y);
            }
        }
    __syncthreads();

    // ================= conv2 =================
    conv_gemm(xs, WT2, col0, nl, quad, acc);

#pragma unroll
    for (int nt = 0; nt < 4; ++nt) {
        pb[nt] = B2[col0 + nt * 16]; ps[nt] = S2[col0 + nt * 16]; pbb[nt] = Bb2[col0 + nt * 16];
    }
#pragma unroll
    for (int mt = 0; mt < 4; ++mt)
#pragma unroll
        for (int nt = 0; nt < 4; ++nt)
#pragma unroll
            for (int r = 0; r < 4; ++r)
                acc[mt][nt][r] = fmaxf(acc[mt][nt][r] + pb[nt], 0.f);
#pragma unroll
    for (int mt = 0; mt < 4; ++mt)
#pragma unroll
        for (int r = 0; r < 4; ++r) {
            float s = acc[mt][0][r] + acc[mt][1][r] + acc[mt][2][r] + acc[mt][3][r];
            float q = acc[mt][0][r] * acc[mt][0][r] + acc[mt][1][r] * acc[mt][1][r] +
                      acc[mt][2][r] * acc[mt][2][r] + acc[mt][3][r] * acc[mt][3][r];
#pragma unroll
            for (int off = 1; off < 16; off <<= 1) { s += __shfl_xor(s, off); q += __shfl_xor(q, off); }
            if (nl == 0) red[16 * mt + 4 * quad + r][w] = make_float2(s, q);
        }
    __syncthreads();
    if (tid < MROWS) {
        const float2 p0 = red[tid][0], p1 = red[tid][1], p2 = red[tid][2], p3 = red[tid][3];
        const float s = p0.x + p1.x + p2.x + p3.x, q = p0.y + p1.y + p2.y + p3.y;
        const float m = s * (1.f / 256.f);
        const float var = q * (1.f / 256.f) - m * m;
        m_l[tid] = m; inv_l[tid] = 1.f / sqrtf(var + 1e-5f);
    }
    __syncthreads();
    // LN2 normalize + dot(lin_w): z per row
    float lwv[4];
#pragma unroll
    for (int nt = 0; nt < 4; ++nt) lwv[nt] = LW[col0 + nt * 16];
#pragma unroll
    for (int mt = 0; mt < 4; ++mt)
#pragma unroll
        for (int r = 0; r < 4; ++r) {
            const int row = 16 * mt + 4 * quad + r;
            const float mm = m_l[row], iv = inv_l[row];
            float z = 0.f;
#pragma unroll
            for (int nt = 0; nt < 4; ++nt) {
                const float y = (acc[mt][nt][r] - mm) * iv * ps[nt] + pbb[nt];
                z = fmaf(y, lwv[nt], z);
            }
#pragma unroll
            for (int off = 1; off < 16; off <<= 1) z += __shfl_xor(z, off);
            if (nl == 0) red[row][w].x = z;
        }
    __syncthreads();
    if (tid < MTW) {
        const int t = t0 + tid;
        if (t < T_) {
            const float z = red[tid][0].x + red[tid][1].x + red[tid][2].x + red[tid][3].x + lbv;
            outp[b * T_ + t] = z;
        }
    }
}

// ---------- fp32 fused predictor (duration path: rint(exp) is flip-sensitive) ----------
// conv1 x-reads are WAVE-UNIFORM -> read directly from global with uniform
// addresses (compiler scalarizes to s_load: SMEM pipe, off the oversubscribed
// LDS pipe which was ~2.2x oversubscribed vs VALU). buf now holds only h1 for
// conv2 (cross-thread exchange still needs LDS). Per-accumulator FMA order
// over (c, tap) is EXACTLY the original serial order -> bit-identical outputs.
template <int MODE>
__global__ __launch_bounds__(256) void predictor_kernel(
    const float* __restrict__ X, const float* __restrict__ W1,
    const float* __restrict__ B1, const float* __restrict__ S1,
    const float* __restrict__ Bb1, const float* __restrict__ W2,
    const float* __restrict__ B2, const float* __restrict__ S2,
    const float* __restrict__ Bb2, const float* __restrict__ LW,
    const float* __restrict__ LB, const int* __restrict__ dscale,
    float* __restrict__ out, int S) {
    __shared__ float buf[E_ * RS];
    __shared__ float red_s[NH][4], red_q[NH][4];
    __shared__ float m_l[NH], inv_l[NH];

    const int tid = threadIdx.x;
    const int lane = tid & 63, wv = tid >> 6;
    const int m0 = blockIdx.x * TW;
    const int b = m0 / S;
    const int t0 = m0 % S;
    const float* Xb = X + (size_t)b * S * E_;

    float a1[NH];
#pragma unroll
    for (int r = 0; r < NH; ++r) a1[r] = 0.f;
    {
        const float* Wf = W1 + tid;
        for (int c = 0; c < E_; c += 4) {
            float wl[12];
#pragma unroll
            for (int cc = 0; cc < 4; ++cc) {
                wl[cc * 3 + 0] = Wf[(0 * E_ + c + cc) * F_];
                wl[cc * 3 + 1] = Wf[(1 * E_ + c + cc) * F_];
                wl[cc * 3 + 2] = Wf[(2 * E_ + c + cc) * F_];
            }
#pragma unroll
            for (int cc = 0; cc < 4; ++cc) {
                // wave-uniform x reads (t0, s, c, cc all uniform) -> s_load
                float xr[NX];
#pragma unroll
                for (int s = 0; s < NX; ++s) {
                    const int tt = t0 - 2 + s;
                    xr[s] = (tt >= 0 && tt < S) ? Xb[(size_t)tt * E_ + (c + cc)] : 0.f;
                }
                const float w0 = wl[cc * 3 + 0], w1 = wl[cc * 3 + 1], w2 = wl[cc * 3 + 2];
#pragma unroll
                for (int r = 0; r < NH; ++r) {
                    a1[r] = fmaf(xr[r],     w0, a1[r]);
                    a1[r] = fmaf(xr[r + 1], w1, a1[r]);
                    a1[r] = fmaf(xr[r + 2], w2, a1[r]);
                }
            }
        }
    }

    const float b1f = B1[tid];
#pragma unroll
    for (int r = 0; r < NH; ++r) a1[r] = fmaxf(a1[r] + b1f, 0.f);

#pragma unroll
    for (int r = 0; r < NH; ++r) {
        float s = a1[r], q = a1[r] * a1[r];
#pragma unroll
        for (int off = 32; off; off >>= 1) { s += __shfl_xor(s, off); q += __shfl_xor(q, off); }
        if (lane == 0) { red_s[r][wv] = s; red_q[r][wv] = q; }
    }
    __syncthreads();
    if (tid < NH) {
        const float s = red_s[tid][0] + red_s[tid][1] + red_s[tid][2] + red_s[tid][3];
        const float q = red_q[tid][0] + red_q[tid][1] + red_q[tid][2] + red_q[tid][3];
        const float m = s * (1.f / F_);
        const float v = q * (1.f / F_) - m * m;
        m_l[tid] = m;
        inv_l[tid] = 1.f / sqrtf(v + 1e-5f);
    }
    __syncthreads();

    const float s1f = S1[tid], sb1 = Bb1[tid];
#pragma unroll
    for (int r = 0; r < NH; ++r) {
        const int th = t0 - 1 + r;
        float y = (a1[r] - m_l[r]) * inv_l[r] * s1f + sb1;
        if (th < 0 || th >= S) y = 0.f;
        buf[tid * RS + r] = y;
    }
    __syncthreads();

    float a2[TW];
#pragma unroll
    for (int p = 0; p < TW; ++p) a2[p] = 0.f;
    {
        const float* Wf = W2 + tid;
        for (int c = 0; c < E_; c += 4) {
            float wl[12];
#pragma unroll
            for (int cc = 0; cc < 4; ++cc) {
                wl[cc * 3 + 0] = Wf[(0 * E_ + c + cc) * F_];
                wl[cc * 3 + 1] = Wf[(1 * E_ + c + cc) * F_];
                wl[cc * 3 + 2] = Wf[(2 * E_ + c + cc) * F_];
            }
#pragma unroll
            for (int h = 0; h < 4; h += 2) {
                const float4* xqa = (const float4*)(&buf[(c + h) * RS]);
                const float4* xqb = (const float4*)(&buf[(c + h + 1) * RS]);
                const float4 a0 = xqa[0], a1q = xqa[1], a2q = xqa[2], a3q = xqa[3], a4q = xqa[4];
                const float4 b0 = xqb[0], b1q = xqb[1], b2q = xqb[2], b3q = xqb[3], b4q = xqb[4];
                {
                    const float xr[NX] = {a0.x, a0.y, a0.z, a0.w, a1q.x, a1q.y, a1q.z, a1q.w,
                                          a2q.x, a2q.y, a2q.z, a2q.w, a3q.x, a3q.y, a3q.z, a3q.w,
                                          a4q.x, a4q.y, a4q.z, a4q.w};
                    const float w0 = wl[h * 3 + 0], w1 = wl[h * 3 + 1], w2 = wl[h * 3 + 2];
#pragma unroll
                    for (int p = 0; p < TW; ++p) {
                        a2[p] = fmaf(xr[p],     w0, a2[p]);
                        a2[p] = fmaf(xr[p + 1], w1, a2[p]);
                        a2[p] = fmaf(xr[p + 2], w2, a2[p]);
                    }
                }
                {
                    const float xr[NX] = {b0.x, b0.y, b0.z, b0.w, b1q.x, b1q.y, b1q.z, b1q.w,
                                          b2q.x, b2q.y, b2q.z, b2q.w, b3q.x, b3q.y, b3q.z, b3q.w,
                                          b4q.x, b4q.y, b4q.z, b4q.w};
                    const float w0 = wl[(h + 1) * 3 + 0], w1 = wl[(h + 1) * 3 + 1], w2 = wl[(h + 1) * 3 + 2];
#pragma unroll
                    for (int p = 0; p < TW; ++p) {
                        a2[p] = fmaf(xr[p],     w0, a2[p]);
                        a2[p] = fmaf(xr[p + 1], w1, a2[p]);
                        a2[p] = fmaf(xr[p + 2], w2, a2[p]);
                    }
                }
            }
        }
    }

    const float b2f = B2[tid];
    float r_[TW];
#pragma unroll
    for (int p = 0; p < TW; ++p) r_[p] = fmaxf(a2[p] + b2f, 0.f);

#pragma unroll
    for (int p = 0; p < TW; ++p) {
        float s = r_[p], q = r_[p] * r_[p];
#pragma unroll
        for (int off = 32; off; off >>= 1) { s += __shfl_xor(s, off); q += __shfl_xor(q, off); }
        if (lane == 0) { red_s[p][wv] = s; red_q[p][wv] = q; }
    }
    __syncthreads();
    if (tid < TW) {
        const float s = red_s[tid][0] + red_s[tid][1] + red_s[tid][2] + red_s[tid][3];
        const float q = red_q[tid][0] + red_q[tid][1] + red_q[tid][2] + red_q[tid][3];
        const float m = s * (1.f / F_);
        const float v = q * (1.f / F_) - m * m;
        m_l[tid] = m;
        inv_l[tid] = 1.f / sqrtf(v + 1e-5f);
    }
    __syncthreads();

    const float s2f = S2[tid], sb2 = Bb2[tid];
    const float lwf = LW[tid];
#pragma unroll
    for (int p = 0; p < TW; ++p) {
        const float y = (r_[p] - m_l[p]) * inv_l[p] * s2f + sb2;
        float z = y * lwf;
#pragma unroll
        for (int off = 32; off; off >>= 1) z += __shfl_xor(z, off);
        if (lane == 0) red_s[p][wv] = z;
    }
    __syncthreads();
    if (tid < TW) {
        float z = red_s[tid][0] + red_s[tid][1] + red_s[tid][2] + red_s[tid][3] + LB[0];
        if (MODE == 1) {
            const float e = expf(z) * (float)dscale[0];
            z = fmaxf(rintf(e), 0.f);
        }
        out[m0 + tid] = z;
    }
}

extern "C" void kernel_launch(void* const* d_in, const int* in_sizes, int n_in,
                              void* d_out, int out_size, void* d_ws, size_t ws_size,
                              hipStream_t stream) {
    (void)in_sizes; (void)n_in; (void)ws_size; (void)out_size;
    const float* hidden = (const float*)d_in[0];
    const int*   dur    = (const int*)d_in[3];
    const float* pt     = (const float*)d_in[4];
    const float* et     = (const float*)d_in[5];
    const int*   dscale = (const int*)d_in[6];
    const float* w1  = (const float*)d_in[7];
    const float* b1  = (const float*)d_in[8];
    const float* s1  = (const float*)d_in[9];
    const float* bb1 = (const float*)d_in[10];
    const float* w2  = (const float*)d_in[11];
    const float* b2  = (const float*)d_in[12];
    const float* s2  = (const float*)d_in[13];
    const float* bb2 = (const float*)d_in[14];
    const float* lw  = (const float*)d_in[15];
    const float* lb  = (const float*)d_in[16];
    const float* pbins = (const float*)d_in[17];
    const float* pemb  = (const float*)d_in[18];
    const float* ebins = (const float*)d_in[19];
    const float* eemb  = (const float*)d_in[20];

    float* out        = (float*)d_out;
    float* out_dur    = out;                       // B*L
    float* out_pitch  = out + 16384;               // B*T
    float* out_energy = out + 147456;              // B*T
    float* ove        = out + 278528;              // B*T*E — final variance_embedding

    u16* wt = (u16*)d_ws;                          // 4 * 196608 u16 = 1.5 MiB
    int* csg = (int*)(wt + 4 * WMAT);              // B*L ints = 64 KiB

    // transposed bf16 weights for pitch/energy convs
    prep_w_kernel<<<(4 * WMAT) / 256, 256, 0, stream>>>(w1, w2, wt);

    // duration cumsum (for fused length-regulation)
    cumsum_kernel<<<B_, 512, 0, stream>>>(dur, csg);

    // duration predictor (fp32)
    predictor_kernel<1><<<(B_ * L_) / TW, 256, 0, stream>>>(
        hidden, w1, b1, s1, bb1, w2, b2, s2, bb2, lw, lb, dscale, out_dur, L_);

    // combined pitch+energy MFMA predictors; energy blocks also emit ve during staging
    mfma_pe_kernel<<<2 * B_ * NBLK, 256, 0, stream>>>(
        hidden, csg, pt, pbins, pemb, et, ebins, eemb, ove, wt,
        b1, s1, bb1, b2, s2, bb2, lw, lb,
        out_pitch, out_energy);
}

// Round 12
// 854.071 us; speedup vs baseline: 1.2739x; 1.2739x over previous
//
#include <hip/hip_runtime.h>
#include <stdint.h>

typedef unsigned short u16;
typedef unsigned int u32;

#define B_ 32
#define L_ 512
#define T_ 4096
#define E_ 256
#define F_ 256

// ---------------- fp32 duration predictor params ----------------
#define TW 16          // output positions per block (fp32 kernel)
#define NH (TW + 2)
#define NX (TW + 4)
#define RS 20

// ---------------- MFMA predictor params ----------------
#define MTW 62         // valid outputs per block
#define MROWS 64       // conv M rows per block (padded)
#define XROWS 66       // staged x rows (t0-2 .. t0+63)
#define XSTR 264       // u16 per LDS row (528 B) -> (nl+quad)%8 bank-group tiling
#define NBLK 67        // ceil(4096/62)
#define KW 768         // GEMM K (3*256)
#define WMAT (KW * F_) // 196608 elements per transposed weight matrix
#define PREPB 1536     // prep blocks in fused setup kernel: 4*WMAT/512

typedef short bf16x8 __attribute__((ext_vector_type(8)));
typedef float f32x4 __attribute__((ext_vector_type(4)));
union Frag { uint4 u; bf16x8 b; };

__device__ __forceinline__ u16 f2b(float f) {
    union { u32 i; float f; } x; x.f = f;
    u32 r = x.i + 0x7FFFu + ((x.i >> 16) & 1u);
    return (u16)(r >> 16);
}

// packed f32x2 -> bf16x2 (RNE), 1 VALU op
__device__ __forceinline__ u32 cvt_pk(float lo, float hi) {
    u32 r;
    asm("v_cvt_pk_bf16_f32 %0, %1, %2" : "=v"(r) : "v"(lo), "v"(hi));
    return r;
}
__device__ __forceinline__ u16 f2b1(float f) {
    u32 r;
    asm("v_cvt_pk_bf16_f32 %0, %1, %2" : "=v"(r) : "v"(f), "v"(f));
    return (u16)r;
}

// ---------- fused setup: weight prep (blocks < PREPB) + duration cumsum ----------
// prep: fp32 [kk][f] -> bf16 transposed [f][kk]; mats 0=p.w1 1=p.w2 2=e.w1 3=e.w2
// cumsum: csg[b][l] = sum_{j<=l} dur[b][j]   (blocks PREPB..PREPB+B_)
__global__ __launch_bounds__(512) void setup_kernel(
    const float* __restrict__ W1all, const float* __restrict__ W2all,
    u16* __restrict__ dst, const int* __restrict__ dur, int* __restrict__ csg) {
    __shared__ int cs[L_];
    const int tid = threadIdx.x;
    if (blockIdx.x < PREPB) {
        const int g = blockIdx.x * 512 + tid;          // 4*196608 total
        const int mat = g / WMAT, rem = g % WMAT;
        const int kk = rem >> 8, f = rem & 255;
        const float* src = ((mat & 1) ? W2all : W1all) + ((mat >> 1) + 1) * (3 * E_ * F_);
        dst[mat * WMAT + f * KW + kk] = f2b(src[kk * 256 + f]);
    } else {
        const int b = blockIdx.x - PREPB;
        cs[tid] = dur[b * L_ + tid];
        __syncthreads();
        for (int off = 1; off < L_; off <<= 1) {
            int t = (tid >= off) ? cs[tid - off] : 0;
            __syncthreads();
            cs[tid] += t;
            __syncthreads();
        }
        csg[b * L_ + tid] = cs[tid];
    }
}

// ---------- conv GEMM (R7 proven form: depth-1 B reg prefetch + setprio) ----------
// A-frag: lane(m=nl, k=quad*8+j); B-frag: lane(n=nl, k=quad*8+j); WT layout [n][kk]
__device__ __forceinline__ void conv_gemm(const u16* xs, const u16* __restrict__ WT,
                                          int col0, int nl, int quad, f32x4 acc[4][4]) {
#pragma unroll
    for (int mt = 0; mt < 4; ++mt)
#pragma unroll
        for (int nt = 0; nt < 4; ++nt) acc[mt][nt] = (f32x4){0.f, 0.f, 0.f, 0.f};
    const u16* wp0 = WT + (size_t)col0 * KW + quad * 8;
    Frag bq[4], bn[4];
#pragma unroll
    for (int nt = 0; nt < 4; ++nt) bq[nt].u = *(const uint4*)(wp0 + nt * (16 * KW));
    for (int s = 0; s < 24; ++s) {
        const int sp = (s + 1 < 24) ? s + 1 : 0;   // uniform clamp, in-bounds
#pragma unroll
        for (int nt = 0; nt < 4; ++nt)
            bn[nt].u = *(const uint4*)(wp0 + nt * (16 * KW) + sp * 32);
        const int kh = s >> 3, c0 = (s & 7) * 32;
        Frag a[4];
#pragma unroll
        for (int mt = 0; mt < 4; ++mt)
            a[mt].u = *(const uint4*)&xs[(16 * mt + nl + kh) * XSTR + c0 + quad * 8];
        __builtin_amdgcn_s_setprio(1);
#pragma unroll
        for (int mt = 0; mt < 4; ++mt)
#pragma unroll
            for (int nt = 0; nt < 4; ++nt)
                acc[mt][nt] = __builtin_amdgcn_mfma_f32_16x16x32_bf16(
                    a[mt].b, bq[nt].b, acc[mt][nt], 0, 0, 0);
        __builtin_amdgcn_s_setprio(0);
#pragma unroll
        for (int nt = 0; nt < 4; ++nt) bq[nt] = bn[nt];
    }
}

// ---------- combined pitch+energy MFMA predictor (R9 best config, verbatim) ----------
// grid = 2*B*NBLK. mat = 0: pitch, input x = LR(hidden).
//                  mat = 1: energy, input x2 = LR(hidden) + pemb[bucket(pt)];
//                           ALSO writes ve = (x + pemb) + eemb[bucket(et)] for its
//                           owned rows during staging (replaces ve_kernel).
__global__ __launch_bounds__(256) void mfma_pe_kernel(
    const float* __restrict__ hidden, const int* __restrict__ csg,
    const float* __restrict__ pt, const float* __restrict__ pbins,
    const float* __restrict__ pemb,
    const float* __restrict__ et, const float* __restrict__ ebins,
    const float* __restrict__ eemb, float* __restrict__ ve,
    const u16* __restrict__ wt,
    const float* __restrict__ b1a, const float* __restrict__ s1a, const float* __restrict__ bb1a,
    const float* __restrict__ b2a, const float* __restrict__ s2a, const float* __restrict__ bb2a,
    const float* __restrict__ lwa, const float* __restrict__ lba,
    float* __restrict__ out_pitch, float* __restrict__ out_energy) {
    __shared__ u16 xs[XROWS * XSTR];          // 34.8 KB; x tile, then h1 tile
    __shared__ float2 red[MROWS][4];
    __shared__ float m_l[MROWS], inv_l[MROWS];
    __shared__ int cs_l[L_];
    __shared__ float bins_l[256];
    __shared__ float bins2_l[256];
    __shared__ int idx_l[XROWS];              // gather source row (-1 = zero)
    __shared__ int kb_l[XROWS];               // pemb bucket per row (mat=1)
    __shared__ int kb2_l[XROWS];              // eemb bucket per row (mat=1)

    const int tid = threadIdx.x;
    const int lane = tid & 63, w = tid >> 6;
    const int nl = lane & 15, quad = lane >> 4;
    const int mat = blockIdx.x / (B_ * NBLK);
    const int rem = blockIdx.x % (B_ * NBLK);
    const int b = rem / NBLK, blk = rem % NBLK;
    const int t0 = blk * MTW;
    const float* Xb = hidden + (size_t)b * (L_ * E_);

    const u16* WT1 = wt + (size_t)(2 * mat) * WMAT;
    const u16* WT2 = wt + (size_t)(2 * mat + 1) * WMAT;
    const float* B1 = b1a + (1 + mat) * F_;
    const float* S1 = s1a + (1 + mat) * F_;
    const float* Bb1 = bb1a + (1 + mat) * F_;
    const float* B2 = b2a + (1 + mat) * F_;
    const float* S2 = s2a + (1 + mat) * F_;
    const float* Bb2 = bb2a + (1 + mat) * F_;
    const float* LW = lwa + (1 + mat) * F_;
    const float lbv = lba[1 + mat];
    float* outp = mat ? out_energy : out_pitch;

    cs_l[tid] = csg[b * L_ + tid];
    cs_l[tid + 256] = csg[b * L_ + 256 + tid];
    if (mat) { bins_l[tid] = pbins[tid]; bins2_l[tid] = ebins[tid]; }
    __syncthreads();
    if (tid < XROWS) {
        const int tt = t0 - 2 + tid;
        int lo = 0, hi = L_;
        while (lo < hi) { int mid = (lo + hi) >> 1; if (cs_l[mid] <= tt) lo = mid + 1; else hi = mid; }
        const bool val = (tt >= 0) && (tt < T_) && (tt < cs_l[L_ - 1]);
        idx_l[tid] = val ? (lo < L_ - 1 ? lo : L_ - 1) : -1;
        int kb = 0, kb2 = 0;
        if (mat && tt >= 0 && tt < T_) {
            const float v = pt[b * T_ + tt];
            int lo2 = 0, hi2 = 256;
            while (lo2 < hi2) { int mid = (lo2 + hi2) >> 1; if (bins_l[mid] < v) lo2 = mid + 1; else hi2 = mid; }
            kb = lo2 > 255 ? 255 : lo2;
            const float v2 = et[b * T_ + tt];
            int lo3 = 0, hi3 = 256;
            while (lo3 < hi3) { int mid = (lo3 + hi3) >> 1; if (bins2_l[mid] < v2) lo3 = mid + 1; else hi3 = mid; }
            kb2 = lo3 > 255 ? 255 : lo3;
        }
        kb_l[tid] = kb;
        kb2_l[tid] = kb2;
    }
    __syncthreads();

    // ---- stage rows 0..65 (pos t0-2+i) as bf16; mat=1 also writes ve ----
    for (int it = 0; it < 17; ++it) {
        const int e = it * 256 + tid;                 // float4 units over 66*64
        if (e < XROWS * 64) {
            const int row = e >> 6, c4 = e & 63;
            const int tt = t0 - 2 + row;
            float4 v = make_float4(0.f, 0.f, 0.f, 0.f);
            const int id = idx_l[row];
            if (id >= 0) v = *(const float4*)(Xb + (size_t)id * E_ + c4 * 4);
            if (mat && tt >= 0 && tt < T_) {
                const float4 ev = *(const float4*)(pemb + (size_t)kb_l[row] * E_ + c4 * 4);
                v.x += ev.x; v.y += ev.y; v.z += ev.z; v.w += ev.w;
                if (row >= 2 && row < 64) {           // owned rows: disjoint across blocks
                    const float4 ee = *(const float4*)(eemb + (size_t)kb2_l[row] * E_ + c4 * 4);
                    float4 o = make_float4(v.x + ee.x, v.y + ee.y, v.z + ee.z, v.w + ee.w);
                    *(float4*)(ve + ((size_t)(b * T_ + tt)) * E_ + c4 * 4) = o;
                }
            }
            uint2 pk = make_uint2(cvt_pk(v.x, v.y), cvt_pk(v.z, v.w));
            *(uint2*)&xs[row * XSTR + c4 * 4] = pk;
        }
    }
    __syncthreads();

    const int col0 = w * 64 + nl;
    f32x4 acc[4][4];

    // ================= conv1 =================
    conv_gemm(xs, WT1, col0, nl, quad, acc);

    float pb[4], ps[4], pbb[4];
#pragma unroll
    for (int nt = 0; nt < 4; ++nt) {
        pb[nt] = B1[col0 + nt * 16]; ps[nt] = S1[col0 + nt * 16]; pbb[nt] = Bb1[col0 + nt * 16];
    }
#pragma unroll
    for (int mt = 0; mt < 4; ++mt)
#pragma unroll
        for (int nt = 0; nt < 4; ++nt)
#pragma unroll
            for (int r = 0; r < 4; ++r)
                acc[mt][nt][r] = fmaxf(acc[mt][nt][r] + pb[nt], 0.f);
    // LN1 stats
#pragma unroll
    for (int mt = 0; mt < 4; ++mt)
#pragma unroll
        for (int r = 0; r < 4; ++r) {
            float s = acc[mt][0][r] + acc[mt][1][r] + acc[mt][2][r] + acc[mt][3][r];
            float q = acc[mt][0][r] * acc[mt][0][r] + acc[mt][1][r] * acc[mt][1][r] +
                      acc[mt][2][r] * acc[mt][2][r] + acc[mt][3][r] * acc[mt][3][r];
#pragma unroll
            for (int off = 1; off < 16; off <<= 1) { s += __shfl_xor(s, off); q += __shfl_xor(q, off); }
            if (nl == 0) red[16 * mt + 4 * quad + r][w] = make_float2(s, q);
        }
    __syncthreads();
    if (tid < MROWS) {
        const float2 p0 = red[tid][0], p1 = red[tid][1], p2 = red[tid][2], p3 = red[tid][3];
        const float s = p0.x + p1.x + p2.x + p3.x, q = p0.y + p1.y + p2.y + p3.y;
        const float m = s * (1.f / 256.f);
        const float var = q * (1.f / 256.f) - m * m;
        m_l[tid] = m; inv_l[tid] = 1.f / sqrtf(var + 1e-5f);
    }
    __syncthreads();
    // normalize -> h1 tile (reuse xs), zero-pad h1 outside sequence
#pragma unroll
    for (int mt = 0; mt < 4; ++mt)
#pragma unroll
        for (int r = 0; r < 4; ++r) {
            const int row = 16 * mt + 4 * quad + r;
            const int th = t0 - 1 + row;
            const float mm = m_l[row], iv = inv_l[row];
#pragma unroll
            for (int nt = 0; nt < 4; ++nt) {
                float y = (acc[mt][nt][r] - mm) * iv * ps[nt] + pbb[nt];
                if (th < 0 || th >= T_) y = 0.f;
                xs[row * XSTR + col0 + nt * 16] = f2b1(y);
            }
        }
    __syncthreads();

    // ================= conv2 =================
    conv_gemm(xs, WT2, col0, nl, quad, acc);

#pragma unroll
    for (int nt = 0; nt < 4; ++nt) {
        pb[nt] = B2[col0 + nt * 16]; ps[nt] = S2[col0 + nt * 16]; pbb[nt] = Bb2[col0 + nt * 16];
    }
#pragma unroll
    for (int mt = 0; mt < 4; ++mt)
#pragma unroll
        for (int nt = 0; nt < 4; ++nt)
#pragma unroll
            for (int r = 0; r < 4; ++r)
                acc[mt][nt][r] = fmaxf(acc[mt][nt][r] + pb[nt], 0.f);
#pragma unroll
    for (int mt = 0; mt < 4; ++mt)
#pragma unroll
        for (int r = 0; r < 4; ++r) {
            float s = acc[mt][0][r] + acc[mt][1][r] + acc[mt][2][r] + acc[mt][3][r];
            float q = acc[mt][0][r] * acc[mt][0][r] + acc[mt][1][r] * acc[mt][1][r] +
                      acc[mt][2][r] * acc[mt][2][r] + acc[mt][3][r] * acc[mt][3][r];
#pragma unroll
            for (int off = 1; off < 16; off <<= 1) { s += __shfl_xor(s, off); q += __shfl_xor(q, off); }
            if (nl == 0) red[16 * mt + 4 * quad + r][w] = make_float2(s, q);
        }
    __syncthreads();
    if (tid < MROWS) {
        const float2 p0 = red[tid][0], p1 = red[tid][1], p2 = red[tid][2], p3 = red[tid][3];
        const float s = p0.x + p1.x + p2.x + p3.x, q = p0.y + p1.y + p2.y + p3.y;
        const float m = s * (1.f / 256.f);
        const float var = q * (1.f / 256.f) - m * m;
        m_l[tid] = m; inv_l[tid] = 1.f / sqrtf(var + 1e-5f);
    }
    __syncthreads();
    // LN2 normalize + dot(lin_w): z per row
    float lwv[4];
#pragma unroll
    for (int nt = 0; nt < 4; ++nt) lwv[nt] = LW[col0 + nt * 16];
#pragma unroll
    for (int mt = 0; mt < 4; ++mt)
#pragma unroll
        for (int r = 0; r < 4; ++r) {
            const int row = 16 * mt + 4 * quad + r;
            const float mm = m_l[row], iv = inv_l[row];
            float z = 0.f;
#pragma unroll
            for (int nt = 0; nt < 4; ++nt) {
                const float y = (acc[mt][nt][r] - mm) * iv * ps[nt] + pbb[nt];
                z = fmaf(y, lwv[nt], z);
            }
#pragma unroll
            for (int off = 1; off < 16; off <<= 1) z += __shfl_xor(z, off);
            if (nl == 0) red[row][w].x = z;
        }
    __syncthreads();
    if (tid < MTW) {
        const int t = t0 + tid;
        if (t < T_) {
            const float z = red[tid][0].x + red[tid][1].x + red[tid][2].x + red[tid][3].x + lbv;
            outp[b * T_ + t] = z;
        }
    }
}

// ---------- fp32 fused predictor (R9 best config, verbatim) ----------
// W loads batched x4; x from LDS buf. Per-accumulator FMA order over (c, tap)
// is EXACTLY the original serial order -> bit-identical duration outputs
// (rint(exp) is flip-sensitive).
template <int MODE>
__global__ __launch_bounds__(256) void predictor_kernel(
    const float* __restrict__ X, const float* __restrict__ W1,
    const float* __restrict__ B1, const float* __restrict__ S1,
    const float* __restrict__ Bb1, const float* __restrict__ W2,
    const float* __restrict__ B2, const float* __restrict__ S2,
    const float* __restrict__ Bb2, const float* __restrict__ LW,
    const float* __restrict__ LB, const int* __restrict__ dscale,
    float* __restrict__ out, int S) {
    __shared__ float buf[E_ * RS];
    __shared__ float red_s[NH][4], red_q[NH][4];
    __shared__ float m_l[NH], inv_l[NH];

    const int tid = threadIdx.x;
    const int lane = tid & 63, wv = tid >> 6;
    const int m0 = blockIdx.x * TW;
    const int b = m0 / S;
    const int t0 = m0 % S;
    const float* Xb = X + (size_t)b * S * E_;

#pragma unroll
    for (int s = 0; s < NX; ++s) {
        const int tt = t0 - 2 + s;
        float v = 0.f;
        if (tt >= 0 && tt < S) v = Xb[(size_t)tt * E_ + tid];
        buf[tid * RS + s] = v;
    }
    __syncthreads();

    float a1[NH];
#pragma unroll
    for (int r = 0; r < NH; ++r) a1[r] = 0.f;
    {
        const float* Wf = W1 + tid;
        for (int c = 0; c < E_; c += 4) {
            float wl[12];
#pragma unroll
            for (int cc = 0; cc < 4; ++cc) {
                wl[cc * 3 + 0] = Wf[(0 * E_ + c + cc) * F_];
                wl[cc * 3 + 1] = Wf[(1 * E_ + c + cc) * F_];
                wl[cc * 3 + 2] = Wf[(2 * E_ + c + cc) * F_];
            }
#pragma unroll
            for (int cc = 0; cc < 4; ++cc) {
                const float4* xq = (const float4*)(&buf[(c + cc) * RS]);
                const float4 q0 = xq[0], q1 = xq[1], q2 = xq[2], q3 = xq[3], q4 = xq[4];
                const float xr[NX] = {q0.x, q0.y, q0.z, q0.w, q1.x, q1.y, q1.z, q1.w,
                                      q2.x, q2.y, q2.z, q2.w, q3.x, q3.y, q3.z, q3.w,
                                      q4.x, q4.y, q4.z, q4.w};
                const float w0 = wl[cc * 3 + 0], w1 = wl[cc * 3 + 1], w2 = wl[cc * 3 + 2];
#pragma unroll
                for (int r = 0; r < NH; ++r) {
                    a1[r] = fmaf(xr[r],     w0, a1[r]);
                    a1[r] = fmaf(xr[r + 1], w1, a1[r]);
                    a1[r] = fmaf(xr[r + 2], w2, a1[r]);
                }
            }
        }
    }
    __syncthreads();

    const float b1f = B1[tid];
#pragma unroll
    for (int r = 0; r < NH; ++r) a1[r] = fmaxf(a1[r] + b1f, 0.f);

#pragma unroll
    for (int r = 0; r < NH; ++r) {
        float s = a1[r], q = a1[r] * a1[r];
#pragma unroll
        for (int off = 32; off; off >>= 1) { s += __shfl_xor(s, off); q += __shfl_xor(q, off); }
        if (lane == 0) { red_s[r][wv] = s; red_q[r][wv] = q; }
    }
    __syncthreads();
    if (tid < NH) {
        const float s = red_s[tid][0] + red_s[tid][1] + red_s[tid][2] + red_s[tid][3];
        const float q = red_q[tid][0] + red_q[tid][1] + red_q[tid][2] + red_q[tid][3];
        const float m = s * (1.f / F_);
        const float v = q * (1.f / F_) - m * m;
        m_l[tid] = m;
        inv_l[tid] = 1.f / sqrtf(v + 1e-5f);
    }
    __syncthreads();

    const float s1f = S1[tid], sb1 = Bb1[tid];
#pragma unroll
    for (int r = 0; r < NH; ++r) {
        const int th = t0 - 1 + r;
        float y = (a1[r] - m_l[r]) * inv_l[r] * s1f + sb1;
        if (th < 0 || th >= S) y = 0.f;
        buf[tid * RS + r] = y;
    }
    __syncthreads();

    float a2[TW];
#pragma unroll
    for (int p = 0; p < TW; ++p) a2[p] = 0.f;
    {
        const float* Wf = W2 + tid;
        for (int c = 0; c < E_; c += 4) {
            float wl[12];
#pragma unroll
            for (int cc = 0; cc < 4; ++cc) {
                wl[cc * 3 + 0] = Wf[(0 * E_ + c + cc) * F_];
                wl[cc * 3 + 1] = Wf[(1 * E_ + c + cc) * F_];
                wl[cc * 3 + 2] = Wf[(2 * E_ + c + cc) * F_];
            }
#pragma unroll
            for (int cc = 0; cc < 4; ++cc) {
                const float4* xq = (const float4*)(&buf[(c + cc) * RS]);
                const float4 q0 = xq[0], q1 = xq[1], q2 = xq[2], q3 = xq[3], q4 = xq[4];
                const float xr[NX] = {q0.x, q0.y, q0.z, q0.w, q1.x, q1.y, q1.z, q1.w,
                                      q2.x, q2.y, q2.z, q2.w, q3.x, q3.y, q3.z, q3.w,
                                      q4.x, q4.y, q4.z, q4.w};
                const float w0 = wl[cc * 3 + 0], w1 = wl[cc * 3 + 1], w2 = wl[cc * 3 + 2];
#pragma unroll
                for (int p = 0; p < TW; ++p) {
                    a2[p] = fmaf(xr[p],     w0, a2[p]);
                    a2[p] = fmaf(xr[p + 1], w1, a2[p]);
                    a2[p] = fmaf(xr[p + 2], w2, a2[p]);
                }
            }
        }
    }

    const float b2f = B2[tid];
    float r_[TW];
#pragma unroll
    for (int p = 0; p < TW; ++p) r_[p] = fmaxf(a2[p] + b2f, 0.f);

#pragma unroll
    for (int p = 0; p < TW; ++p) {
        float s = r_[p], q = r_[p] * r_[p];
#pragma unroll
        for (int off = 32; off; off >>= 1) { s += __shfl_xor(s, off); q += __shfl_xor(q, off); }
        if (lane == 0) { red_s[p][wv] = s; red_q[p][wv] = q; }
    }
    __syncthreads();
    if (tid < TW) {
        const float s = red_s[tid][0] + red_s[tid][1] + red_s[tid][2] + red_s[tid][3];
        const float q = red_q[tid][0] + red_q[tid][1] + red_q[tid][2] + red_q[tid][3];
        const float m = s * (1.f / F_);
        const float v = q * (1.f / F_) - m * m;
        m_l[tid] = m;
        inv_l[tid] = 1.f / sqrtf(v + 1e-5f);
    }
    __syncthreads();

    const float s2f = S2[tid], sb2 = Bb2[tid];
    const float lwf = LW[tid];
#pragma unroll
    for (int p = 0; p < TW; ++p) {
        const float y = (r_[p] - m_l[p]) * inv_l[p] * s2f + sb2;
        float z = y * lwf;
#pragma unroll
        for (int off = 32; off; off >>= 1) z += __shfl_xor(z, off);
        if (lane == 0) red_s[p][wv] = z;
    }
    __syncthreads();
    if (tid < TW) {
        float z = red_s[tid][0] + red_s[tid][1] + red_s[tid][2] + red_s[tid][3] + LB[0];
        if (MODE == 1) {
            const float e = expf(z) * (float)dscale[0];
            z = fmaxf(rintf(e), 0.f);
        }
        out[m0 + tid] = z;
    }
}

extern "C" void kernel_launch(void* const* d_in, const int* in_sizes, int n_in,
                              void* d_out, int out_size, void* d_ws, size_t ws_size,
                              hipStream_t stream) {
    (void)in_sizes; (void)n_in; (void)ws_size; (void)out_size;
    const float* hidden = (const float*)d_in[0];
    const int*   dur    = (const int*)d_in[3];
    const float* pt     = (const float*)d_in[4];
    const float* et     = (const float*)d_in[5];
    const int*   dscale = (const int*)d_in[6];
    const float* w1  = (const float*)d_in[7];
    const float* b1  = (const float*)d_in[8];
    const float* s1  = (const float*)d_in[9];
    const float* bb1 = (const float*)d_in[10];
    const float* w2  = (const float*)d_in[11];
    const float* b2  = (const float*)d_in[12];
    const float* s2  = (const float*)d_in[13];
    const float* bb2 = (const float*)d_in[14];
    const float* lw  = (const float*)d_in[15];
    const float* lb  = (const float*)d_in[16];
    const float* pbins = (const float*)d_in[17];
    const float* pemb  = (const float*)d_in[18];
    const float* ebins = (const float*)d_in[19];
    const float* eemb  = (const float*)d_in[20];

    float* out        = (float*)d_out;
    float* out_dur    = out;                       // B*L
    float* out_pitch  = out + 16384;               // B*T
    float* out_energy = out + 147456;              // B*T
    float* ove        = out + 278528;              // B*T*E — final variance_embedding

    u16* wt = (u16*)d_ws;                          // 4 * 196608 u16 = 1.5 MiB
    int* csg = (int*)(wt + 4 * WMAT);              // B*L ints = 64 KiB

    // fused setup: transposed bf16 weights + duration cumsum (one launch)
    setup_kernel<<<PREPB + B_, 512, 0, stream>>>(w1, w2, wt, dur, csg);

    // duration predictor (fp32)
    predictor_kernel<1><<<(B_ * L_) / TW, 256, 0, stream>>>(
        hidden, w1, b1, s1, bb1, w2, b2, s2, bb2, lw, lb, dscale, out_dur, L_);

    // combined pitch+energy MFMA predictors; energy blocks also emit ve during staging
    mfma_pe_kernel<<<2 * B_ * NBLK, 256, 0, stream>>>(
        hidden, csg, pt, pbins, pemb, et, ebins, eemb, ove, wt,
        b1, s1, bb1, b2, s2, bb2, lw, lb,
        out_pitch, out_energy);
}